// Round 14
// baseline (174.493 us; speedup 1.0000x reference)
//
#include <hip/hip_runtime.h>
#include <hip/hip_bf16.h>
#include <stdint.h>

typedef __bf16 bf16_t;
typedef __attribute__((ext_vector_type(8))) __bf16 bf16x8;
typedef __attribute__((ext_vector_type(4))) __bf16 bf16x4;
typedef __attribute__((ext_vector_type(4))) float f32x4;

#define NHEADS 32
#define HDIM 128
#define NKV 8
#define GQ 4
#define BATCH 8
#define SEQ 1024
#define TOTAL (BATCH * SEQ)
#define QD (NHEADS * HDIM)   // 4096
#define KVD (NKV * HDIM)     // 1024
#define ATT_SCALE 0.08838834764831845f
#define QSCL (0.08838834764831845f * 1.4426950408889634f)

#define QBLK 64
#define KBLK 64            // v1 fallback tile
#define KT2 128            // v13 main-kernel k-tile
#define NQT (SEQ / QBLK)   // 16

__device__ __forceinline__ void gload16(const bf16_t* g, bf16_t* l) {
    __builtin_amdgcn_global_load_lds(
        (const __attribute__((address_space(1))) void*)g,
        (__attribute__((address_space(3))) void*)l,
        16, 0, 0);
}

// proven in m214v22 / v8: pack two f32 -> u32 of 2 bf16 (lo = src0, hi = src1)
__device__ __forceinline__ uint32_t cvt_pk_bf16(float lo, float hi) {
    uint32_t r;
    asm("v_cvt_pk_bf16_f32 %0, %1, %2" : "=v"(r) : "v"(lo), "v"(hi));
    return r;
}

// ===========================================================================
// Pre-pass: K fp32 -> bf16 (same layout); V fp32 -> bf16 TRANSPOSED with
// k-column PERMUTATION within each 64-token block:
//   k = (k5 k4 k3 k2 k1 k0) -> pos = k5<<5 | k3<<4 | k2<<3 | k4<<2 | k1 k0
// Makes the PV B-fragment match the k's a lane holds in-register after the
// swapped QK^T -> P->A pack is fully in-lane. (128-wide tiles are two
// 64-blocks; the property is per-64-block, so it carries over.)
// ===========================================================================
__global__ __launch_bounds__(256)
void attn_prepass_kernel(const float* __restrict__ kg, const float* __restrict__ vg,
                         bf16_t* __restrict__ kws, bf16_t* __restrict__ vtws)
{
    const int bid = blockIdx.x;
    const int tid = threadIdx.x;
    if (bid < 512) {
        __shared__ bf16_t Lt[128 * 130];
        const int b  = bid >> 6;
        const int hk = (bid >> 3) & 7;
        const int tt = bid & 7;
        const float* vp = vg + ((long)(b * SEQ + tt * 128)) * KVD + hk * HDIM;
        #pragma unroll
        for (int it = 0; it < 16; ++it) {
            int idx = it * 256 + tid;
            int t  = idx >> 5;
            int c4 = (idx & 31) * 4;
            float4 f = *(const float4*)(vp + (long)t * KVD + c4);
            Lt[(c4 + 0) * 130 + t] = (bf16_t)f.x;
            Lt[(c4 + 1) * 130 + t] = (bf16_t)f.y;
            Lt[(c4 + 2) * 130 + t] = (bf16_t)f.z;
            Lt[(c4 + 3) * 130 + t] = (bf16_t)f.w;
        }
        __syncthreads();
        bf16_t* op = vtws + ((long)((b * NKV + hk) * HDIM)) * SEQ + tt * 128;
        #pragma unroll
        for (int jt = 0; jt < 8; ++jt) {
            int jdx = jt * 256 + tid;
            int d  = jdx >> 4;          // 0..127
            int c8 = (jdx & 15) * 8;    // 0..120 (8-aligned)
            const bf16_t* lp = &Lt[d * 130 + c8];
            uint32_t u0 = *(const uint32_t*)(lp + 0);
            uint32_t u1 = *(const uint32_t*)(lp + 2);
            uint32_t u2 = *(const uint32_t*)(lp + 4);
            uint32_t u3 = *(const uint32_t*)(lp + 6);
            // chunk base kl0 (bits k5,k4,k3) -> pos base p0 = k5<<5|k3<<4|k4<<2
            int kl0 = c8 & 63;
            int p0  = (kl0 & 32) | ((kl0 & 8) << 1) | ((kl0 & 16) >> 2);
            bf16_t* dst = op + (long)d * SEQ + (c8 & ~63);
            uint2 lo; lo.x = u0; lo.y = u1;     // k2=0: j=0..3
            uint2 hi; hi.x = u2; hi.y = u3;     // k2=1: j=0..3
            *(uint2*)(dst + p0)     = lo;
            *(uint2*)(dst + p0 + 8) = hi;
        }
    } else {
        const long total4 = (long)TOTAL * KVD / 4;
        const float4* k4 = (const float4*)kg;
        for (long i = (long)(bid - 512) * 256 + tid; i < total4; i += 1024L * 256) {
            float4 f = k4[i];
            bf16x4 o4;
            o4[0] = (bf16_t)f.x; o4[1] = (bf16_t)f.y;
            o4[2] = (bf16_t)f.z; o4[3] = (bf16_t)f.w;
            *(bf16x4*)(kws + i * 4) = o4;
        }
    }
}

// ===========================================================================
// Main attention kernel (v13): KBLK=128 + FULL-GQA-GROUP BLOCK.
//   r13 lesson: LDS traffic isn't binding (v12 halved it, got slower by
//   dropping waves); the binding cost is the per-tile barrier-synced serial
//   chain x number of sync events, hidden only by resident-wave diversity.
//   v13 keeps 16 waves/CU AND halves sync events: 1024-thread block =
//   4 heads x 4 row-slots (whole GQA group), k-tiles of 128 cols, 2-deep
//   buffers = 128KB LDS, 1 block/CU. Per block-phase: 9 tiles vs v11's 17
//   -> half the vmcnt/barrier/chain-latency events; K/V staging HBM traffic
//   halves again (4 heads share one stage).
//   All v11 machinery otherwise: swapped QK^T in-reg softmax, in-lane pack
//   via V k-perm, issue-1-ahead single barrier, XOR swizzles, slim softmax,
//   balanced q-tile pairing, rsum partials, hoisted staging addresses.
//   Mask on the (always-last) diagonal tile: dqfs = (qt&1)*4 + fs;
//   skip kb > dqfs; boundary kb == dqfs masks (l4*4+j > l16) as before.
// ===========================================================================
__global__ __launch_bounds__(1024)
void attn_fwd_v13(const float* __restrict__ qg, const bf16_t* __restrict__ kws,
                  const bf16_t* __restrict__ vtws, float* __restrict__ og)
{
    __shared__ __align__(16) bf16_t Kl[2][KT2 * HDIM];   // 2 x 32KB, [128][128]
    __shared__ __align__(16) bf16_t Vl[2][HDIM * KT2];   // 2 x 32KB, [128][128]

    const int tid  = threadIdx.x;
    const int w    = tid >> 6;    // 0..15
    const int lane = tid & 63;
    const int l16  = lane & 15;
    const int l4   = lane >> 4;   // 0..3

    const int bid = blockIdx.x;        // 0..511
    const int bh  = bid & 63;
    const int pi  = bid >> 6;          // 0..7
    const int b   = bh >> 3;
    const int hk  = bh & 7;
    const int g   = w >> 2;            // head within kv group (0..3)
    const int fs  = w & 3;             // 16-row slot in 64-row q-tile
    const int h   = hk * GQ + g;

    const bf16_t* kbase = kws + (long)(b * SEQ) * KVD + hk * HDIM;
    const bf16_t* vbase = vtws + (long)((b * NKV + hk) * HDIM) * SEQ;

    // ---- tile-invariant per-lane staging offsets (2 K + 2 V chunks/wave) ----
    long koff[2], voff[2];
    int ldst[2];
    #pragma unroll
    for (int i = 0; i < 2; ++i) {
        int c = w * 2 + i;                 // 0..31
        int r = c * 4 + (lane >> 4);       // K row 0..127
        koff[i] = (long)r * KVD + (((lane & 15) ^ (r & 7)) * 8);
        int d  = c * 4 + (lane >> 4);      // V d-row 0..127
        int e0 = (lane & 15) * 8;          // elem 0..120 in the 128-col row
        voff[i] = (long)d * SEQ + (e0 & 64) + ((e0 & 63) ^ ((d & 7) << 3));
        ldst[i] = c * 512;                 // 4 rows x 128 elems
    }
    const long KT_STRIDE = (long)KT2 * KVD;

    for (int ph = 0; ph < 2; ++ph) {
        const int qt = ph ? pi : (NQT - 1 - pi);   // heavy q-tile first
        const long qtok0 = (long)b * SEQ + qt * QBLK;

        // ---- Q fragments (B-op): col = l16 (q-row), k-slots d = s*32+l4*8+e ----
        bf16x8 aq[4];
        {
            const float* qp = qg + (qtok0 + fs * 16 + l16) * QD + h * HDIM + l4 * 8;
            #pragma unroll
            for (int s = 0; s < 4; ++s) {
                float4 x = *(const float4*)(qp + s * 32);
                float4 y = *(const float4*)(qp + s * 32 + 4);
                bf16x8 t;
                t[0] = (bf16_t)(x.x * QSCL); t[1] = (bf16_t)(x.y * QSCL);
                t[2] = (bf16_t)(x.z * QSCL); t[3] = (bf16_t)(x.w * QSCL);
                t[4] = (bf16_t)(y.x * QSCL); t[5] = (bf16_t)(y.y * QSCL);
                t[6] = (bf16_t)(y.z * QSCL); t[7] = (bf16_t)(y.w * QSCL);
                aq[s] = t;
            }
        }
        __builtin_amdgcn_sched_barrier(0);
        __syncthreads();   // phase boundary: prev phase's LDS reads done

        f32x4 accO[8];
        #pragma unroll
        for (int n = 0; n < 8; ++n) accO[n] = (f32x4){0.f, 0.f, 0.f, 0.f};
        float rsum[4] = {0.f, 0.f, 0.f, 0.f};

        const bf16_t* kn = kbase;
        const bf16_t* vn = vbase;
        auto issue_tile = [&](int buf) {
            gload16(kn + koff[0], &Kl[buf][ldst[0]]);
            gload16(kn + koff[1], &Kl[buf][ldst[1]]);
            gload16(vn + voff[0], &Vl[buf][ldst[0]]);
            gload16(vn + voff[1], &Vl[buf][ldst[1]]);
            kn += KT_STRIDE;
            vn += KT2;
        };

        const int nkt  = (qt >> 1) + 1;            // 128-wide tiles
        const int dqfs = ((qt & 1) << 2) + fs;     // boundary kb on last tile
        issue_tile(0);

        for (int kt = 0; kt < nkt; ++kt) {
            const bf16_t* Kc = &Kl[kt & 1][0];
            const bf16_t* Vc = &Vl[kt & 1][0];
            asm volatile("s_waitcnt vmcnt(0)" ::: "memory");
            __builtin_amdgcn_s_barrier();
            if (kt + 1 < nkt) issue_tile((kt + 1) & 1);
            __builtin_amdgcn_sched_barrier(0);

            const bool diag = (kt == nkt - 1);     // last tile holds the diagonal

            // ---- T = K Q^T per 16-col sub-block (8 of them); softmax; pack ----
            uint32_t u[8][2];
            #pragma unroll
            for (int kb = 0; kb < 8; ++kb) { u[kb][0] = 0; u[kb][1] = 0; }

            #pragma unroll
            for (int kb = 0; kb < 8; ++kb) {
                const bool skip = diag && (kb > dqfs);
                if (!skip) {
                    f32x4 t = (f32x4){0.f, 0.f, 0.f, 0.f};
                    __builtin_amdgcn_s_setprio(1);
                    #pragma unroll
                    for (int s = 0; s < 4; ++s) {
                        int elem = (s * 32 + l4 * 8) ^ ((l16 & 7) << 3);
                        bf16x8 bk = *(const bf16x8*)(Kc + (kb * 16 + l16) * 128 + elem);
                        t = __builtin_amdgcn_mfma_f32_16x16x32_bf16(bk, aq[s], t, 0, 0, 0);
                    }
                    __builtin_amdgcn_s_setprio(0);
                    const bool needmask = diag && (kb == dqfs);
                    #pragma unroll
                    for (int j = 0; j < 4; ++j) {
                        float p = exp2f(t[j]);
                        if (needmask && (l4 * 4 + j > l16)) p = 0.f;
                        t[j] = p;
                        rsum[j] += p;
                    }
                    u[kb][0] = cvt_pk_bf16(t[0], t[1]);
                    u[kb][1] = cvt_pk_bf16(t[2], t[3]);
                }
            }

            // ---- P -> PV A-frags: IN-LANE (V k-perm makes B match) ----
            bf16x8 pa[4];
            #pragma unroll
            for (int ks = 0; ks < 4; ++ks) {
                union { uint32_t uu[4]; bf16x8 v; } pk;
                pk.uu[0] = u[ks * 2][0];
                pk.uu[1] = u[ks * 2][1];
                pk.uu[2] = u[ks * 2 + 1][0];
                pk.uu[3] = u[ks * 2 + 1][1];
                pa[ks] = pk.v;
            }

            // ---- O += P V over 128 k-cols (4 ks slots) ----
            __builtin_amdgcn_s_setprio(1);
            #pragma unroll
            for (int n = 0; n < 8; ++n) {
                #pragma unroll
                for (int ks = 0; ks < 4; ++ks) {
                    int elem = (((ks & 1) * 32 + l4 * 8) ^ ((l16 & 7) << 3)) + ((ks >> 1) * 64);
                    bf16x8 bv = *(const bf16x8*)(Vc + (n * 16 + l16) * 128 + elem);
                    accO[n] = __builtin_amdgcn_mfma_f32_16x16x32_bf16(pa[ks], bv, accO[n], 0, 0, 0);
                }
            }
            __builtin_amdgcn_s_setprio(0);
            // no end-of-tile barrier (issue-1-ahead scheme)
        }

        // ---- epilogue: combine partials, reduce over l4 group, store ----
        float rs = (rsum[0] + rsum[1]) + (rsum[2] + rsum[3]);
        rs += __shfl_xor(rs, 16);
        rs += __shfl_xor(rs, 32);
        float inv = 1.f / rs;   // valid for q-row = l16 on every lane
        #pragma unroll
        for (int j = 0; j < 4; ++j) {
            const int qr = l4 * 4 + j;
            float invr = __shfl(inv, qr);   // lane qr holds q-row qr's inv
            float* op = og + (qtok0 + fs * 16 + qr) * QD + h * HDIM + l16;
            #pragma unroll
            for (int n = 0; n < 8; ++n)
                op[n * 16] = accO[n][j] * invr;
        }
    }
}

// ===========================================================================
// Fallback (round-1 kernel) if ws is too small for the bf16 pre-pass.
// ===========================================================================
#define KPAD 136
#define VPAD 72
#define PPAD 72
__global__ __launch_bounds__(512, 2)
void attn_fwd_v1(const float* __restrict__ qg, const float* __restrict__ kg,
                 const float* __restrict__ vg, float* __restrict__ og)
{
    __shared__ bf16_t Kl[KBLK * KPAD];
    __shared__ bf16_t Vt[HDIM * VPAD];
    __shared__ bf16_t Pl[8 * 16 * PPAD];

    const int tid  = threadIdx.x;
    const int w    = tid >> 6;
    const int lane = tid & 63;
    const int l4   = lane >> 4;
    const int l16  = lane & 15;

    const int bid = blockIdx.x;
    const int bh  = bid % 64;
    const int qt  = (NQT - 1) - bid / 64;
    const int b   = bh / NKV;
    const int hk  = bh % NKV;
    const int g   = w >> 1;
    const int h   = hk * GQ + g;
    const int rh  = (w & 1) * 32;

    const long qtok0 = (long)b * SEQ + qt * QBLK;

    bf16x8 aq[2][4];
    #pragma unroll
    for (int f = 0; f < 2; ++f) {
        const float* qp = qg + (qtok0 + rh + f * 16 + l16) * QD + h * HDIM + l4 * 8;
        #pragma unroll
        for (int s = 0; s < 4; ++s) {
            float4 x = *(const float4*)(qp + s * 32);
            float4 y = *(const float4*)(qp + s * 32 + 4);
            bf16x8 t;
            t[0] = (bf16_t)x.x; t[1] = (bf16_t)x.y; t[2] = (bf16_t)x.z; t[3] = (bf16_t)x.w;
            t[4] = (bf16_t)y.x; t[5] = (bf16_t)y.y; t[6] = (bf16_t)y.z; t[7] = (bf16_t)y.w;
            aq[f][s] = t;
        }
    }

    f32x4 accO[2][8];
    float mrun[2][4], lsum[2][4];
    #pragma unroll
    for (int f = 0; f < 2; ++f) {
        #pragma unroll
        for (int n = 0; n < 8; ++n) accO[f][n] = (f32x4){0.f, 0.f, 0.f, 0.f};
        #pragma unroll
        for (int j = 0; j < 4; ++j) { mrun[f][j] = -1e30f; lsum[f][j] = 0.f; }
    }

    const long ktok0 = (long)b * SEQ;
    const int nkt = qt + 1;

    for (int kt = 0; kt < nkt; ++kt) {
        __syncthreads();
        const float* kp = kg + (ktok0 + kt * KBLK) * KVD + hk * HDIM;
        const float* vp = vg + (ktok0 + kt * KBLK) * KVD + hk * HDIM;
        #pragma unroll
        for (int it = 0; it < 4; ++it) {
            int idx = it * 512 + tid;
            int row = idx >> 5;
            int c4  = (idx & 31) * 4;
            float4 kf = *(const float4*)(kp + (long)row * KVD + c4);
            bf16x4 k4;
            k4[0] = (bf16_t)kf.x; k4[1] = (bf16_t)kf.y; k4[2] = (bf16_t)kf.z; k4[3] = (bf16_t)kf.w;
            *(bf16x4*)(&Kl[row * KPAD + c4]) = k4;
            float4 vf = *(const float4*)(vp + (long)row * KVD + c4);
            const float* vfa = (const float*)&vf;
            #pragma unroll
            for (int m = 0; m < 4; ++m) {
                int d   = c4 + m;
                int blk = (row >> 3) ^ ((d >> 3) & 7);
                Vt[d * VPAD + blk * 8 + (row & 7)] = (bf16_t)vfa[m];
            }
        }
        __syncthreads();

        const bool diag = (kt == qt);
        bf16_t* pw = &Pl[w * 16 * PPAD];

        #pragma unroll
        for (int f = 0; f < 2; ++f) {
            f32x4 accS[4];
            #pragma unroll
            for (int n = 0; n < 4; ++n) {
                f32x4 acc = (f32x4){0.f, 0.f, 0.f, 0.f};
                #pragma unroll
                for (int s = 0; s < 4; ++s) {
                    bf16x8 bk = *(const bf16x8*)(&Kl[(n * 16 + l16) * KPAD + s * 32 + l4 * 8]);
                    acc = __builtin_amdgcn_mfma_f32_16x16x32_bf16(aq[f][s], bk, acc, 0, 0, 0);
                }
                accS[n] = acc;
            }

            const int qrow_loc = rh + f * 16 + l4 * 4;
            float pm[4];
            #pragma unroll
            for (int j = 0; j < 4; ++j) pm[j] = -1e30f;
            #pragma unroll
            for (int n = 0; n < 4; ++n) {
                #pragma unroll
                for (int j = 0; j < 4; ++j) {
                    float sv = accS[n][j] * ATT_SCALE;
                    if (diag && (n * 16 + l16 > qrow_loc + j)) sv = -1e30f;
                    accS[n][j] = sv;
                    pm[j] = fmaxf(pm[j], sv);
                }
            }
            #pragma unroll
            for (int j = 0; j < 4; ++j) {
                float m0 = pm[j];
                m0 = fmaxf(m0, __shfl_xor(m0, 1));
                m0 = fmaxf(m0, __shfl_xor(m0, 2));
                m0 = fmaxf(m0, __shfl_xor(m0, 4));
                m0 = fmaxf(m0, __shfl_xor(m0, 8));
                pm[j] = m0;
            }
            float al[4], rs[4];
            #pragma unroll
            for (int j = 0; j < 4; ++j) {
                float mnew = fmaxf(mrun[f][j], pm[j]);
                al[j] = __expf(mrun[f][j] - mnew);
                mrun[f][j] = mnew;
                rs[j] = 0.f;
            }
            #pragma unroll
            for (int n = 0; n < 4; ++n) {
                #pragma unroll
                for (int j = 0; j < 4; ++j) {
                    float p = __expf(accS[n][j] - mrun[f][j]);
                    accS[n][j] = p;
                    rs[j] += p;
                }
            }
            #pragma unroll
            for (int j = 0; j < 4; ++j) {
                float r = rs[j];
                r += __shfl_xor(r, 1);
                r += __shfl_xor(r, 2);
                r += __shfl_xor(r, 4);
                r += __shfl_xor(r, 8);
                lsum[f][j] = lsum[f][j] * al[j] + r;
            }
            #pragma unroll
            for (int n = 0; n < 8; ++n) {
                #pragma unroll
                for (int j = 0; j < 4; ++j) accO[f][n][j] *= al[j];
            }
            #pragma unroll
            for (int n = 0; n < 4; ++n) {
                #pragma unroll
                for (int j = 0; j < 4; ++j)
                    pw[(l4 * 4 + j) * PPAD + n * 16 + l16] = (bf16_t)accS[n][j];
            }
            asm volatile("s_waitcnt lgkmcnt(0)" ::: "memory");
            __builtin_amdgcn_sched_barrier(0);
            #pragma unroll
            for (int ks = 0; ks < 2; ++ks) {
                bf16x8 ap = *(const bf16x8*)(&pw[l16 * PPAD + ks * 32 + l4 * 8]);
                #pragma unroll
                for (int n = 0; n < 8; ++n) {
                    int d   = n * 16 + l16;
                    int blk = (ks * 4 + l4) ^ ((d >> 3) & 7);
                    bf16x8 bv = *(const bf16x8*)(&Vt[d * VPAD + blk * 8]);
                    accO[f][n] = __builtin_amdgcn_mfma_f32_16x16x32_bf16(ap, bv, accO[f][n], 0, 0, 0);
                }
            }
        }
    }

    #pragma unroll
    for (int f = 0; f < 2; ++f) {
        #pragma unroll
        for (int j = 0; j < 4; ++j) {
            float inv = 1.f / lsum[f][j];
            float* op = og + (qtok0 + rh + f * 16 + l4 * 4 + j) * QD + h * HDIM;
            #pragma unroll
            for (int n = 0; n < 8; ++n)
                op[n * 16 + l16] = accO[f][n][j] * inv;
        }
    }
}

extern "C" void kernel_launch(void* const* d_in, const int* in_sizes, int n_in,
                              void* d_out, int out_size, void* d_ws, size_t ws_size,
                              hipStream_t stream) {
    const float* q = (const float*)d_in[0];
    const float* k = (const float*)d_in[1];
    const float* v = (const float*)d_in[2];
    float* o = (float*)d_out;

    const size_t kws_elems = (size_t)TOTAL * KVD;            // 8,388,608
    const size_t vws_elems = (size_t)BATCH * NKV * HDIM * SEQ;
    const size_t need = (kws_elems + vws_elems) * sizeof(bf16_t);  // 33.5 MB

    if (ws_size >= need) {
        bf16_t* kws  = (bf16_t*)d_ws;
        bf16_t* vtws = kws + kws_elems;
        attn_prepass_kernel<<<1536, 256, 0, stream>>>(k, v, kws, vtws);
        attn_fwd_v13<<<512, 1024, 0, stream>>>(q, kws, vtws, o);
    } else {
        attn_fwd_v1<<<NQT * BATCH * NKV, 512, 0, stream>>>(q, k, v, o);
    }
}

// Round 15
// 144.055 us; speedup vs baseline: 1.2113x; 1.2113x over previous
//
#include <hip/hip_runtime.h>
#include <hip/hip_bf16.h>
#include <stdint.h>

typedef __bf16 bf16_t;
typedef __attribute__((ext_vector_type(8))) __bf16 bf16x8;
typedef __attribute__((ext_vector_type(4))) __bf16 bf16x4;
typedef __attribute__((ext_vector_type(4))) float f32x4;

#define NHEADS 32
#define HDIM 128
#define NKV 8
#define GQ 4
#define BATCH 8
#define SEQ 1024
#define TOTAL (BATCH * SEQ)
#define QD (NHEADS * HDIM)   // 4096
#define KVD (NKV * HDIM)     // 1024
#define ATT_SCALE 0.08838834764831845f
#define QSCL (0.08838834764831845f * 1.4426950408889634f)

#define QBLK 64
#define KBLK 64
#define NQT (SEQ / QBLK)     // 16

__device__ __forceinline__ void gload16(const bf16_t* g, bf16_t* l) {
    __builtin_amdgcn_global_load_lds(
        (const __attribute__((address_space(1))) void*)g,
        (__attribute__((address_space(3))) void*)l,
        16, 0, 0);
}

// proven in m214v22 / v8: pack two f32 -> u32 of 2 bf16 (lo = src0, hi = src1)
__device__ __forceinline__ uint32_t cvt_pk_bf16(float lo, float hi) {
    uint32_t r;
    asm("v_cvt_pk_bf16_f32 %0, %1, %2" : "=v"(r) : "v"(lo), "v"(hi));
    return r;
}

// ===========================================================================
// Pre-pass: K fp32 -> bf16 (same layout); V fp32 -> bf16 TRANSPOSED with
// k-column PERMUTATION within each 64-token block:
//   k = (k5 k4 k3 k2 k1 k0) -> pos = k5<<5 | k3<<4 | k2<<3 | k4<<2 | k1 k0
// Makes the PV B-fragment (chunk ks*4+l4) match the k's a lane holds
// in-register after the swapped QK^T -> P->A pack is fully in-lane.
// ===========================================================================
__global__ __launch_bounds__(256)
void attn_prepass_kernel(const float* __restrict__ kg, const float* __restrict__ vg,
                         bf16_t* __restrict__ kws, bf16_t* __restrict__ vtws)
{
    const int bid = blockIdx.x;
    const int tid = threadIdx.x;
    if (bid < 512) {
        __shared__ bf16_t Lt[128 * 130];
        const int b  = bid >> 6;
        const int hk = (bid >> 3) & 7;
        const int tt = bid & 7;
        const float* vp = vg + ((long)(b * SEQ + tt * 128)) * KVD + hk * HDIM;
        #pragma unroll
        for (int it = 0; it < 16; ++it) {
            int idx = it * 256 + tid;
            int t  = idx >> 5;
            int c4 = (idx & 31) * 4;
            float4 f = *(const float4*)(vp + (long)t * KVD + c4);
            Lt[(c4 + 0) * 130 + t] = (bf16_t)f.x;
            Lt[(c4 + 1) * 130 + t] = (bf16_t)f.y;
            Lt[(c4 + 2) * 130 + t] = (bf16_t)f.z;
            Lt[(c4 + 3) * 130 + t] = (bf16_t)f.w;
        }
        __syncthreads();
        bf16_t* op = vtws + ((long)((b * NKV + hk) * HDIM)) * SEQ + tt * 128;
        #pragma unroll
        for (int jt = 0; jt < 8; ++jt) {
            int jdx = jt * 256 + tid;
            int d  = jdx >> 4;          // 0..127
            int c8 = (jdx & 15) * 8;    // 0..120 (8-aligned)
            const bf16_t* lp = &Lt[d * 130 + c8];
            uint32_t u0 = *(const uint32_t*)(lp + 0);
            uint32_t u1 = *(const uint32_t*)(lp + 2);
            uint32_t u2 = *(const uint32_t*)(lp + 4);
            uint32_t u3 = *(const uint32_t*)(lp + 6);
            // chunk base kl0 (bits k5,k4,k3) -> pos base p0 = k5<<5|k3<<4|k4<<2
            int kl0 = c8 & 63;
            int p0  = (kl0 & 32) | ((kl0 & 8) << 1) | ((kl0 & 16) >> 2);
            bf16_t* dst = op + (long)d * SEQ + (c8 & ~63);
            uint2 lo; lo.x = u0; lo.y = u1;     // k2=0: j=0..3
            uint2 hi; hi.x = u2; hi.y = u3;     // k2=1: j=0..3
            *(uint2*)(dst + p0)     = lo;
            *(uint2*)(dst + p0 + 8) = hi;
        }
    } else {
        const long total4 = (long)TOTAL * KVD / 4;
        const float4* k4 = (const float4*)kg;
        for (long i = (long)(bid - 512) * 256 + tid; i < total4; i += 1024L * 256) {
            float4 f = k4[i];
            bf16x4 o4;
            o4[0] = (bf16_t)f.x; o4[1] = (bf16_t)f.y;
            o4[2] = (bf16_t)f.z; o4[3] = (bf16_t)f.w;
            *(bf16x4*)(kws + i * 4) = o4;
        }
    }
}

// ===========================================================================
// Main attention kernel (v14 = v11 + XCD-aware block mapping).
//   v11 was the best structure (main 133.5us): swapped QK^T in-reg softmax,
//   in-lane P->A pack via V k-perm, 2-deep gload_lds staging, issue-1-ahead
//   single barrier/tile, XOR swizzle, slim softmax, balanced q-tile pairing,
//   2 heads/block, launch_bounds(512,4) -> 2 independent blocks/CU.
//   v13 (KBLK=128, 1024-thr) spilled (WRITE_SIZE 173MB) and regressed.
//   v14 changes ONLY the bid decode: bid%8 == hk, so all 16 blocks sharing
//   one (b,hk) K/V stream land on one XCD (8 streams x 512KB = 4MB = one
//   XCD L2) -> K/V staging reads become L2-local (T1).
// ===========================================================================
__global__ __launch_bounds__(512, 4)
void attn_fwd_v14(const float* __restrict__ qg, const bf16_t* __restrict__ kws,
                  const bf16_t* __restrict__ vtws, float* __restrict__ og)
{
    __shared__ __align__(16) bf16_t Kl[2][KBLK * HDIM];   // 2 x 16KB, [64][128]
    __shared__ __align__(16) bf16_t Vl[2][HDIM * KBLK];   // 2 x 16KB, [128][64]

    const int tid  = threadIdx.x;
    const int w    = tid >> 6;    // 0..7
    const int lane = tid & 63;
    const int l16  = lane & 15;
    const int l4   = lane >> 4;   // 0..3

    // XCD-aware decode: hk in the low 3 bits (HW maps bid%8 -> XCD).
    const int bid = blockIdx.x;        // 0..1023
    const int hk  = bid & 7;
    const int m   = bid >> 3;          // 0..127
    const int hp  = m & 1;             // head-pair within kv group
    const int b   = (m >> 1) & 7;
    const int pi  = m >> 4;            // 0..7
    const int g2  = w >> 2;            // head within pair
    const int fs  = w & 3;             // 16-row slot in 64-row q-tile
    const int h   = hk * GQ + hp * 2 + g2;

    const bf16_t* kbase = kws + (long)(b * SEQ) * KVD + hk * HDIM;
    const bf16_t* vbase = vtws + (long)((b * NKV + hk) * HDIM) * SEQ;
    const int kc0 = w * 2;

    // ---- tile-invariant per-lane staging offsets ----
    long koff[2], voff[2];
    int ldst[2];
    #pragma unroll
    for (int i = 0; i < 2; ++i) {
        int c = kc0 + i;
        int r = c * 4 + (lane >> 4);
        koff[i] = (long)r * KVD + (((lane & 15) ^ (r & 7)) * 8);
        int d = c * 8 + (lane >> 3);
        voff[i] = (long)d * SEQ + (((lane & 7) ^ (d & 7)) * 8);
        ldst[i] = c * 512;
    }
    const long KT_STRIDE = (long)KBLK * KVD;   // 65536 elems

    for (int ph = 0; ph < 2; ++ph) {
        const int qt = ph ? pi : (NQT - 1 - pi);   // heavy q-tile first
        const long qtok0 = (long)b * SEQ + qt * QBLK;

        // ---- Q fragments (B-op): col = l16 (q-row), k-slots d = s*32+l4*8+e ----
        bf16x8 aq[4];
        {
            const float* qp = qg + (qtok0 + fs * 16 + l16) * QD + h * HDIM + l4 * 8;
            #pragma unroll
            for (int s = 0; s < 4; ++s) {
                float4 x = *(const float4*)(qp + s * 32);
                float4 y = *(const float4*)(qp + s * 32 + 4);
                bf16x8 t;
                t[0] = (bf16_t)(x.x * QSCL); t[1] = (bf16_t)(x.y * QSCL);
                t[2] = (bf16_t)(x.z * QSCL); t[3] = (bf16_t)(x.w * QSCL);
                t[4] = (bf16_t)(y.x * QSCL); t[5] = (bf16_t)(y.y * QSCL);
                t[6] = (bf16_t)(y.z * QSCL); t[7] = (bf16_t)(y.w * QSCL);
                aq[s] = t;
            }
        }
        __builtin_amdgcn_sched_barrier(0);
        __syncthreads();   // phase boundary: prev phase's LDS reads done

        f32x4 accO[8];
        #pragma unroll
        for (int n = 0; n < 8; ++n) accO[n] = (f32x4){0.f, 0.f, 0.f, 0.f};
        float rsum[4] = {0.f, 0.f, 0.f, 0.f};

        const bf16_t* kn = kbase;
        const bf16_t* vn = vbase;
        auto issue_tile = [&](int buf) {
            gload16(kn + koff[0], &Kl[buf][ldst[0]]);
            gload16(kn + koff[1], &Kl[buf][ldst[1]]);
            gload16(vn + voff[0], &Vl[buf][ldst[0]]);
            gload16(vn + voff[1], &Vl[buf][ldst[1]]);
            kn += KT_STRIDE;
            vn += KBLK;
        };

        const int nkt = qt + 1;
        issue_tile(0);

        for (int kt = 0; kt < nkt; ++kt) {
            const bf16_t* Kc = &Kl[kt & 1][0];
            const bf16_t* Vc = &Vl[kt & 1][0];
            // own loads for tile kt are the only outstanding ones here
            asm volatile("s_waitcnt vmcnt(0)" ::: "memory");
            __builtin_amdgcn_s_barrier();
            if (kt + 1 < nkt) issue_tile((kt + 1) & 1);
            __builtin_amdgcn_sched_barrier(0);

            const bool diag = (kt == qt);

            // ---- T = K Q^T per 16-col sub-block; in-reg softmax; cvt_pk ----
            uint32_t u[4][2];
            #pragma unroll
            for (int kb = 0; kb < 4; ++kb) { u[kb][0] = 0; u[kb][1] = 0; }

            #pragma unroll
            for (int kb = 0; kb < 4; ++kb) {
                const bool skip = diag && (kb > fs);
                if (!skip) {
                    f32x4 t = (f32x4){0.f, 0.f, 0.f, 0.f};
                    __builtin_amdgcn_s_setprio(1);
                    #pragma unroll
                    for (int s = 0; s < 4; ++s) {
                        int elem = (s * 32 + l4 * 8) ^ ((l16 & 7) << 3);
                        bf16x8 bk = *(const bf16x8*)(Kc + (kb * 16 + l16) * 128 + elem);
                        t = __builtin_amdgcn_mfma_f32_16x16x32_bf16(bk, aq[s], t, 0, 0, 0);
                    }
                    __builtin_amdgcn_s_setprio(0);
                    const bool needmask = diag && (kb == fs);
                    #pragma unroll
                    for (int j = 0; j < 4; ++j) {
                        float p = exp2f(t[j]);
                        if (needmask && (kb * 16 + l4 * 4 + j > fs * 16 + l16)) p = 0.f;
                        t[j] = p;
                        rsum[j] += p;   // 4 independent chains
                    }
                    u[kb][0] = cvt_pk_bf16(t[0], t[1]);
                    u[kb][1] = cvt_pk_bf16(t[2], t[3]);
                }
            }

            // ---- P -> PV A-frags: IN-LANE (V k-perm makes B match) ----
            bf16x8 pa[2];
            #pragma unroll
            for (int ks = 0; ks < 2; ++ks) {
                union { uint32_t uu[4]; bf16x8 v; } pk;
                pk.uu[0] = u[ks * 2][0];
                pk.uu[1] = u[ks * 2][1];
                pk.uu[2] = u[ks * 2 + 1][0];
                pk.uu[3] = u[ks * 2 + 1][1];
                pa[ks] = pk.v;
            }

            // ---- O += P V ----
            __builtin_amdgcn_s_setprio(1);
            #pragma unroll
            for (int n = 0; n < 8; ++n) {
                #pragma unroll
                for (int ks = 0; ks < 2; ++ks) {
                    int elem = (ks * 32 + l4 * 8) ^ ((l16 & 7) << 3);
                    bf16x8 bv = *(const bf16x8*)(Vc + (n * 16 + l16) * 64 + elem);
                    accO[n] = __builtin_amdgcn_mfma_f32_16x16x32_bf16(pa[ks], bv, accO[n], 0, 0, 0);
                }
            }
            __builtin_amdgcn_s_setprio(0);
            // no end-of-tile barrier (issue-1-ahead scheme)
        }

        // ---- epilogue: combine partials, reduce over l4 group, store ----
        float rs = (rsum[0] + rsum[1]) + (rsum[2] + rsum[3]);
        rs += __shfl_xor(rs, 16);
        rs += __shfl_xor(rs, 32);
        float inv = 1.f / rs;   // valid for q-row = l16 on every lane
        #pragma unroll
        for (int j = 0; j < 4; ++j) {
            const int qr = l4 * 4 + j;
            float invr = __shfl(inv, qr);   // lane qr holds q-row qr's inv
            float* op = og + (qtok0 + fs * 16 + qr) * QD + h * HDIM + l16;
            #pragma unroll
            for (int n = 0; n < 8; ++n)
                op[n * 16] = accO[n][j] * invr;
        }
    }
}

// ===========================================================================
// Fallback (round-1 kernel) if ws is too small for the bf16 pre-pass.
// ===========================================================================
#define KPAD 136
#define VPAD 72
#define PPAD 72
__global__ __launch_bounds__(512, 2)
void attn_fwd_v1(const float* __restrict__ qg, const float* __restrict__ kg,
                 const float* __restrict__ vg, float* __restrict__ og)
{
    __shared__ bf16_t Kl[KBLK * KPAD];
    __shared__ bf16_t Vt[HDIM * VPAD];
    __shared__ bf16_t Pl[8 * 16 * PPAD];

    const int tid  = threadIdx.x;
    const int w    = tid >> 6;
    const int lane = tid & 63;
    const int l4   = lane >> 4;
    const int l16  = lane & 15;

    const int bid = blockIdx.x;
    const int bh  = bid % 64;
    const int qt  = (NQT - 1) - bid / 64;
    const int b   = bh / NKV;
    const int hk  = bh % NKV;
    const int g   = w >> 1;
    const int h   = hk * GQ + g;
    const int rh  = (w & 1) * 32;

    const long qtok0 = (long)b * SEQ + qt * QBLK;

    bf16x8 aq[2][4];
    #pragma unroll
    for (int f = 0; f < 2; ++f) {
        const float* qp = qg + (qtok0 + rh + f * 16 + l16) * QD + h * HDIM + l4 * 8;
        #pragma unroll
        for (int s = 0; s < 4; ++s) {
            float4 x = *(const float4*)(qp + s * 32);
            float4 y = *(const float4*)(qp + s * 32 + 4);
            bf16x8 t;
            t[0] = (bf16_t)x.x; t[1] = (bf16_t)x.y; t[2] = (bf16_t)x.z; t[3] = (bf16_t)x.w;
            t[4] = (bf16_t)y.x; t[5] = (bf16_t)y.y; t[6] = (bf16_t)y.z; t[7] = (bf16_t)y.w;
            aq[f][s] = t;
        }
    }

    f32x4 accO[2][8];
    float mrun[2][4], lsum[2][4];
    #pragma unroll
    for (int f = 0; f < 2; ++f) {
        #pragma unroll
        for (int n = 0; n < 8; ++n) accO[f][n] = (f32x4){0.f, 0.f, 0.f, 0.f};
        #pragma unroll
        for (int j = 0; j < 4; ++j) { mrun[f][j] = -1e30f; lsum[f][j] = 0.f; }
    }

    const long ktok0 = (long)b * SEQ;
    const int nkt = qt + 1;

    for (int kt = 0; kt < nkt; ++kt) {
        __syncthreads();
        const float* kp = kg + (ktok0 + kt * KBLK) * KVD + hk * HDIM;
        const float* vp = vg + (ktok0 + kt * KBLK) * KVD + hk * HDIM;
        #pragma unroll
        for (int it = 0; it < 4; ++it) {
            int idx = it * 512 + tid;
            int row = idx >> 5;
            int c4  = (idx & 31) * 4;
            float4 kf = *(const float4*)(kp + (long)row * KVD + c4);
            bf16x4 k4;
            k4[0] = (bf16_t)kf.x; k4[1] = (bf16_t)kf.y; k4[2] = (bf16_t)kf.z; k4[3] = (bf16_t)kf.w;
            *(bf16x4*)(&Kl[row * KPAD + c4]) = k4;
            float4 vf = *(const float4*)(vp + (long)row * KVD + c4);
            const float* vfa = (const float*)&vf;
            #pragma unroll
            for (int m = 0; m < 4; ++m) {
                int d   = c4 + m;
                int blk = (row >> 3) ^ ((d >> 3) & 7);
                Vt[d * VPAD + blk * 8 + (row & 7)] = (bf16_t)vfa[m];
            }
        }
        __syncthreads();

        const bool diag = (kt == qt);
        bf16_t* pw = &Pl[w * 16 * PPAD];

        #pragma unroll
        for (int f = 0; f < 2; ++f) {
            f32x4 accS[4];
            #pragma unroll
            for (int n = 0; n < 4; ++n) {
                f32x4 acc = (f32x4){0.f, 0.f, 0.f, 0.f};
                #pragma unroll
                for (int s = 0; s < 4; ++s) {
                    bf16x8 bk = *(const bf16x8*)(&Kl[(n * 16 + l16) * KPAD + s * 32 + l4 * 8]);
                    acc = __builtin_amdgcn_mfma_f32_16x16x32_bf16(aq[f][s], bk, acc, 0, 0, 0);
                }
                accS[n] = acc;
            }

            const int qrow_loc = rh + f * 16 + l4 * 4;
            float pm[4];
            #pragma unroll
            for (int j = 0; j < 4; ++j) pm[j] = -1e30f;
            #pragma unroll
            for (int n = 0; n < 4; ++n) {
                #pragma unroll
                for (int j = 0; j < 4; ++j) {
                    float sv = accS[n][j] * ATT_SCALE;
                    if (diag && (n * 16 + l16 > qrow_loc + j)) sv = -1e30f;
                    accS[n][j] = sv;
                    pm[j] = fmaxf(pm[j], sv);
                }
            }
            #pragma unroll
            for (int j = 0; j < 4; ++j) {
                float m0 = pm[j];
                m0 = fmaxf(m0, __shfl_xor(m0, 1));
                m0 = fmaxf(m0, __shfl_xor(m0, 2));
                m0 = fmaxf(m0, __shfl_xor(m0, 4));
                m0 = fmaxf(m0, __shfl_xor(m0, 8));
                pm[j] = m0;
            }
            float al[4], rs[4];
            #pragma unroll
            for (int j = 0; j < 4; ++j) {
                float mnew = fmaxf(mrun[f][j], pm[j]);
                al[j] = __expf(mrun[f][j] - mnew);
                mrun[f][j] = mnew;
                rs[j] = 0.f;
            }
            #pragma unroll
            for (int n = 0; n < 4; ++n) {
                #pragma unroll
                for (int j = 0; j < 4; ++j) {
                    float p = __expf(accS[n][j] - mrun[f][j]);
                    accS[n][j] = p;
                    rs[j] += p;
                }
            }
            #pragma unroll
            for (int j = 0; j < 4; ++j) {
                float r = rs[j];
                r += __shfl_xor(r, 1);
                r += __shfl_xor(r, 2);
                r += __shfl_xor(r, 4);
                r += __shfl_xor(r, 8);
                lsum[f][j] = lsum[f][j] * al[j] + r;
            }
            #pragma unroll
            for (int n = 0; n < 8; ++n) {
                #pragma unroll
                for (int j = 0; j < 4; ++j) accO[f][n][j] *= al[j];
            }
            #pragma unroll
            for (int n = 0; n < 4; ++n) {
                #pragma unroll
                for (int j = 0; j < 4; ++j)
                    pw[(l4 * 4 + j) * PPAD + n * 16 + l16] = (bf16_t)accS[n][j];
            }
            asm volatile("s_waitcnt lgkmcnt(0)" ::: "memory");
            __builtin_amdgcn_sched_barrier(0);
            #pragma unroll
            for (int ks = 0; ks < 2; ++ks) {
                bf16x8 ap = *(const bf16x8*)(&pw[l16 * PPAD + ks * 32 + l4 * 8]);
                #pragma unroll
                for (int n = 0; n < 8; ++n) {
                    int d   = n * 16 + l16;
                    int blk = (ks * 4 + l4) ^ ((d >> 3) & 7);
                    bf16x8 bv = *(const bf16x8*)(&Vt[d * VPAD + blk * 8]);
                    accO[f][n] = __builtin_amdgcn_mfma_f32_16x16x32_bf16(ap, bv, accO[f][n], 0, 0, 0);
                }
            }
        }
    }

    #pragma unroll
    for (int f = 0; f < 2; ++f) {
        #pragma unroll
        for (int j = 0; j < 4; ++j) {
            float inv = 1.f / lsum[f][j];
            float* op = og + (qtok0 + rh + f * 16 + l4 * 4 + j) * QD + h * HDIM;
            #pragma unroll
            for (int n = 0; n < 8; ++n)
                op[n * 16 + l16] = accO[f][n][j] * inv;
        }
    }
}

extern "C" void kernel_launch(void* const* d_in, const int* in_sizes, int n_in,
                              void* d_out, int out_size, void* d_ws, size_t ws_size,
                              hipStream_t stream) {
    const float* q = (const float*)d_in[0];
    const float* k = (const float*)d_in[1];
    const float* v = (const float*)d_in[2];
    float* o = (float*)d_out;

    const size_t kws_elems = (size_t)TOTAL * KVD;            // 8,388,608
    const size_t vws_elems = (size_t)BATCH * NKV * HDIM * SEQ;
    const size_t need = (kws_elems + vws_elems) * sizeof(bf16_t);  // 33.5 MB

    if (ws_size >= need) {
        bf16_t* kws  = (bf16_t*)d_ws;
        bf16_t* vtws = kws + kws_elems;
        attn_prepass_kernel<<<1536, 256, 0, stream>>>(k, v, kws, vtws);
        attn_fwd_v14<<<1024, 512, 0, stream>>>(q, kws, vtws, o);
    } else {
        attn_fwd_v1<<<NQT * BATCH * NKV, 512, 0, stream>>>(q, k, v, o);
    }
}

// Round 16
// 140.603 us; speedup vs baseline: 1.2410x; 1.0246x over previous
//
#include <hip/hip_runtime.h>
#include <hip/hip_bf16.h>
#include <stdint.h>

typedef __bf16 bf16_t;
typedef __attribute__((ext_vector_type(8))) __bf16 bf16x8;
typedef __attribute__((ext_vector_type(4))) __bf16 bf16x4;
typedef __attribute__((ext_vector_type(4))) float f32x4;

#define NHEADS 32
#define HDIM 128
#define NKV 8
#define GQ 4
#define BATCH 8
#define SEQ 1024
#define TOTAL (BATCH * SEQ)
#define QD (NHEADS * HDIM)   // 4096
#define KVD (NKV * HDIM)     // 1024
#define ATT_SCALE 0.08838834764831845f
#define QSCL (0.08838834764831845f * 1.4426950408889634f)

#define QBLK 64
#define KBLK 64
#define NQT (SEQ / QBLK)     // 16

#if __has_builtin(__builtin_amdgcn_exp2f)
#define EXP2F __builtin_amdgcn_exp2f   // raw v_exp_f32; args bounded ~|30|
#else
#define EXP2F exp2f
#endif

__device__ __forceinline__ void gload16(const bf16_t* g, bf16_t* l) {
    __builtin_amdgcn_global_load_lds(
        (const __attribute__((address_space(1))) void*)g,
        (__attribute__((address_space(3))) void*)l,
        16, 0, 0);
}

// proven in m214v22 / v8: pack two f32 -> u32 of 2 bf16 (lo = src0, hi = src1)
__device__ __forceinline__ uint32_t cvt_pk_bf16(float lo, float hi) {
    uint32_t r;
    asm("v_cvt_pk_bf16_f32 %0, %1, %2" : "=v"(r) : "v"(lo), "v"(hi));
    return r;
}

// ===========================================================================
// Pre-pass: K fp32 -> bf16 (same layout); V fp32 -> bf16 TRANSPOSED with
// k-column PERMUTATION within each 64-token block:
//   k = (k5 k4 k3 k2 k1 k0) -> pos = k5<<5 | k3<<4 | k2<<3 | k4<<2 | k1 k0
// Makes the PV B-fragment (chunk ks*4+l4) match the k's a lane holds
// in-register after the swapped QK^T -> P->A pack is fully in-lane.
// ===========================================================================
__global__ __launch_bounds__(256)
void attn_prepass_kernel(const float* __restrict__ kg, const float* __restrict__ vg,
                         bf16_t* __restrict__ kws, bf16_t* __restrict__ vtws)
{
    const int bid = blockIdx.x;
    const int tid = threadIdx.x;
    if (bid < 512) {
        __shared__ bf16_t Lt[128 * 130];
        const int b  = bid >> 6;
        const int hk = (bid >> 3) & 7;
        const int tt = bid & 7;
        const float* vp = vg + ((long)(b * SEQ + tt * 128)) * KVD + hk * HDIM;
        #pragma unroll
        for (int it = 0; it < 16; ++it) {
            int idx = it * 256 + tid;
            int t  = idx >> 5;
            int c4 = (idx & 31) * 4;
            float4 f = *(const float4*)(vp + (long)t * KVD + c4);
            Lt[(c4 + 0) * 130 + t] = (bf16_t)f.x;
            Lt[(c4 + 1) * 130 + t] = (bf16_t)f.y;
            Lt[(c4 + 2) * 130 + t] = (bf16_t)f.z;
            Lt[(c4 + 3) * 130 + t] = (bf16_t)f.w;
        }
        __syncthreads();
        bf16_t* op = vtws + ((long)((b * NKV + hk) * HDIM)) * SEQ + tt * 128;
        #pragma unroll
        for (int jt = 0; jt < 8; ++jt) {
            int jdx = jt * 256 + tid;
            int d  = jdx >> 4;          // 0..127
            int c8 = (jdx & 15) * 8;    // 0..120 (8-aligned)
            const bf16_t* lp = &Lt[d * 130 + c8];
            uint32_t u0 = *(const uint32_t*)(lp + 0);
            uint32_t u1 = *(const uint32_t*)(lp + 2);
            uint32_t u2 = *(const uint32_t*)(lp + 4);
            uint32_t u3 = *(const uint32_t*)(lp + 6);
            // chunk base kl0 (bits k5,k4,k3) -> pos base p0 = k5<<5|k3<<4|k4<<2
            int kl0 = c8 & 63;
            int p0  = (kl0 & 32) | ((kl0 & 8) << 1) | ((kl0 & 16) >> 2);
            bf16_t* dst = op + (long)d * SEQ + (c8 & ~63);
            uint2 lo; lo.x = u0; lo.y = u1;     // k2=0: j=0..3
            uint2 hi; hi.x = u2; hi.y = u3;     // k2=1: j=0..3
            *(uint2*)(dst + p0)     = lo;
            *(uint2*)(dst + p0 + 8) = hi;
        }
    } else {
        const long total4 = (long)TOTAL * KVD / 4;
        const float4* k4 = (const float4*)kg;
        for (long i = (long)(bid - 512) * 256 + tid; i < total4; i += 1024L * 256) {
            float4 f = k4[i];
            bf16x4 o4;
            o4[0] = (bf16_t)f.x; o4[1] = (bf16_t)f.y;
            o4[2] = (bf16_t)f.z; o4[3] = (bf16_t)f.w;
            *(bf16x4*)(kws + i * 4) = o4;
        }
    }
}

// ===========================================================================
// Main attention kernel (v15 = v14 + QK dependency-chain break + raw exp2).
//   v14 structure unchanged (swapped QK^T in-reg softmax, in-lane P->A pack
//   via V k-perm, 2-deep gload_lds staging, issue-1-ahead single barrier,
//   XOR swizzle, balanced pairing, XCD-aware bid decode, 2 blocks/CU).
//   NEW: (1) the 4 per-kb QK MFMA chains (each 4-deep serially dependent
//   through the accumulator) are computed under ONE setprio region with no
//   per-kb fences -> scheduler interleaves 4 independent chains, amortizing
//   ~560 cycles of accumulator-dependency latency per tile per wave (the
//   old per-kb setprio toggles acted as scheduling fences). Softmax+pack
//   runs as a second pass over t[4]. (2) exp2f -> __builtin_amdgcn_exp2f
//   (raw v_exp_f32; OCML denormal fixup is dead for our bounded args).
// ===========================================================================
__global__ __launch_bounds__(512, 4)
void attn_fwd_v15(const float* __restrict__ qg, const bf16_t* __restrict__ kws,
                  const bf16_t* __restrict__ vtws, float* __restrict__ og)
{
    __shared__ __align__(16) bf16_t Kl[2][KBLK * HDIM];   // 2 x 16KB, [64][128]
    __shared__ __align__(16) bf16_t Vl[2][HDIM * KBLK];   // 2 x 16KB, [128][64]

    const int tid  = threadIdx.x;
    const int w    = tid >> 6;    // 0..7
    const int lane = tid & 63;
    const int l16  = lane & 15;
    const int l4   = lane >> 4;   // 0..3

    // XCD-aware decode: hk in the low 3 bits (HW maps bid%8 -> XCD).
    const int bid = blockIdx.x;        // 0..1023
    const int hk  = bid & 7;
    const int m   = bid >> 3;          // 0..127
    const int hp  = m & 1;             // head-pair within kv group
    const int b   = (m >> 1) & 7;
    const int pi  = m >> 4;            // 0..7
    const int g2  = w >> 2;            // head within pair
    const int fs  = w & 3;             // 16-row slot in 64-row q-tile
    const int h   = hk * GQ + hp * 2 + g2;

    const bf16_t* kbase = kws + (long)(b * SEQ) * KVD + hk * HDIM;
    const bf16_t* vbase = vtws + (long)((b * NKV + hk) * HDIM) * SEQ;
    const int kc0 = w * 2;

    // ---- tile-invariant per-lane staging offsets ----
    long koff[2], voff[2];
    int ldst[2];
    #pragma unroll
    for (int i = 0; i < 2; ++i) {
        int c = kc0 + i;
        int r = c * 4 + (lane >> 4);
        koff[i] = (long)r * KVD + (((lane & 15) ^ (r & 7)) * 8);
        int d = c * 8 + (lane >> 3);
        voff[i] = (long)d * SEQ + (((lane & 7) ^ (d & 7)) * 8);
        ldst[i] = c * 512;
    }
    const long KT_STRIDE = (long)KBLK * KVD;   // 65536 elems

    for (int ph = 0; ph < 2; ++ph) {
        const int qt = ph ? pi : (NQT - 1 - pi);   // heavy q-tile first
        const long qtok0 = (long)b * SEQ + qt * QBLK;

        // ---- Q fragments (B-op): col = l16 (q-row), k-slots d = s*32+l4*8+e ----
        bf16x8 aq[4];
        {
            const float* qp = qg + (qtok0 + fs * 16 + l16) * QD + h * HDIM + l4 * 8;
            #pragma unroll
            for (int s = 0; s < 4; ++s) {
                float4 x = *(const float4*)(qp + s * 32);
                float4 y = *(const float4*)(qp + s * 32 + 4);
                bf16x8 t;
                t[0] = (bf16_t)(x.x * QSCL); t[1] = (bf16_t)(x.y * QSCL);
                t[2] = (bf16_t)(x.z * QSCL); t[3] = (bf16_t)(x.w * QSCL);
                t[4] = (bf16_t)(y.x * QSCL); t[5] = (bf16_t)(y.y * QSCL);
                t[6] = (bf16_t)(y.z * QSCL); t[7] = (bf16_t)(y.w * QSCL);
                aq[s] = t;
            }
        }
        __builtin_amdgcn_sched_barrier(0);
        __syncthreads();   // phase boundary: prev phase's LDS reads done

        f32x4 accO[8];
        #pragma unroll
        for (int n = 0; n < 8; ++n) accO[n] = (f32x4){0.f, 0.f, 0.f, 0.f};
        float rsum[4] = {0.f, 0.f, 0.f, 0.f};

        const bf16_t* kn = kbase;
        const bf16_t* vn = vbase;
        auto issue_tile = [&](int buf) {
            gload16(kn + koff[0], &Kl[buf][ldst[0]]);
            gload16(kn + koff[1], &Kl[buf][ldst[1]]);
            gload16(vn + voff[0], &Vl[buf][ldst[0]]);
            gload16(vn + voff[1], &Vl[buf][ldst[1]]);
            kn += KT_STRIDE;
            vn += KBLK;
        };

        const int nkt = qt + 1;
        issue_tile(0);

        for (int kt = 0; kt < nkt; ++kt) {
            const bf16_t* Kc = &Kl[kt & 1][0];
            const bf16_t* Vc = &Vl[kt & 1][0];
            // own loads for tile kt are the only outstanding ones here
            asm volatile("s_waitcnt vmcnt(0)" ::: "memory");
            __builtin_amdgcn_s_barrier();
            if (kt + 1 < nkt) issue_tile((kt + 1) & 1);
            __builtin_amdgcn_sched_barrier(0);

            const bool diag = (kt == qt);

            // ---- QK: 4 INDEPENDENT MFMA chains, one setprio region, no
            //      per-kb fences -> scheduler interleaves the chains ----
            f32x4 t[4];
            __builtin_amdgcn_s_setprio(1);
            #pragma unroll
            for (int kb = 0; kb < 4; ++kb) {
                if (!(diag && (kb > fs))) {
                    f32x4 acc = (f32x4){0.f, 0.f, 0.f, 0.f};
                    #pragma unroll
                    for (int s = 0; s < 4; ++s) {
                        int elem = (s * 32 + l4 * 8) ^ ((l16 & 7) << 3);
                        bf16x8 bk = *(const bf16x8*)(Kc + (kb * 16 + l16) * 128 + elem);
                        acc = __builtin_amdgcn_mfma_f32_16x16x32_bf16(bk, aq[s], acc, 0, 0, 0);
                    }
                    t[kb] = acc;
                }
            }
            __builtin_amdgcn_s_setprio(0);

            // ---- softmax + pack as a second pass over t[4] ----
            uint32_t u[4][2];
            #pragma unroll
            for (int kb = 0; kb < 4; ++kb) { u[kb][0] = 0; u[kb][1] = 0; }
            #pragma unroll
            for (int kb = 0; kb < 4; ++kb) {
                if (!(diag && (kb > fs))) {
                    const bool needmask = diag && (kb == fs);
                    #pragma unroll
                    for (int j = 0; j < 4; ++j) {
                        float p = EXP2F(t[kb][j]);
                        if (needmask && (kb * 16 + l4 * 4 + j > fs * 16 + l16)) p = 0.f;
                        t[kb][j] = p;
                        rsum[j] += p;   // 4 independent chains
                    }
                    u[kb][0] = cvt_pk_bf16(t[kb][0], t[kb][1]);
                    u[kb][1] = cvt_pk_bf16(t[kb][2], t[kb][3]);
                }
            }

            // ---- P -> PV A-frags: IN-LANE (V k-perm makes B match) ----
            bf16x8 pa[2];
            #pragma unroll
            for (int ks = 0; ks < 2; ++ks) {
                union { uint32_t uu[4]; bf16x8 v; } pk;
                pk.uu[0] = u[ks * 2][0];
                pk.uu[1] = u[ks * 2][1];
                pk.uu[2] = u[ks * 2 + 1][0];
                pk.uu[3] = u[ks * 2 + 1][1];
                pa[ks] = pk.v;
            }

            // ---- O += P V ----
            __builtin_amdgcn_s_setprio(1);
            #pragma unroll
            for (int n = 0; n < 8; ++n) {
                #pragma unroll
                for (int ks = 0; ks < 2; ++ks) {
                    int elem = (ks * 32 + l4 * 8) ^ ((l16 & 7) << 3);
                    bf16x8 bv = *(const bf16x8*)(Vc + (n * 16 + l16) * 64 + elem);
                    accO[n] = __builtin_amdgcn_mfma_f32_16x16x32_bf16(pa[ks], bv, accO[n], 0, 0, 0);
                }
            }
            __builtin_amdgcn_s_setprio(0);
            // no end-of-tile barrier (issue-1-ahead scheme)
        }

        // ---- epilogue: combine partials, reduce over l4 group, store ----
        float rs = (rsum[0] + rsum[1]) + (rsum[2] + rsum[3]);
        rs += __shfl_xor(rs, 16);
        rs += __shfl_xor(rs, 32);
        float inv = 1.f / rs;   // valid for q-row = l16 on every lane
        #pragma unroll
        for (int j = 0; j < 4; ++j) {
            const int qr = l4 * 4 + j;
            float invr = __shfl(inv, qr);   // lane qr holds q-row qr's inv
            float* op = og + (qtok0 + fs * 16 + qr) * QD + h * HDIM + l16;
            #pragma unroll
            for (int n = 0; n < 8; ++n)
                op[n * 16] = accO[n][j] * invr;
        }
    }
}

// ===========================================================================
// Fallback (round-1 kernel) if ws is too small for the bf16 pre-pass.
// ===========================================================================
#define KPAD 136
#define VPAD 72
#define PPAD 72
__global__ __launch_bounds__(512, 2)
void attn_fwd_v1(const float* __restrict__ qg, const float* __restrict__ kg,
                 const float* __restrict__ vg, float* __restrict__ og)
{
    __shared__ bf16_t Kl[KBLK * KPAD];
    __shared__ bf16_t Vt[HDIM * VPAD];
    __shared__ bf16_t Pl[8 * 16 * PPAD];

    const int tid  = threadIdx.x;
    const int w    = tid >> 6;
    const int lane = tid & 63;
    const int l4   = lane >> 4;
    const int l16  = lane & 15;

    const int bid = blockIdx.x;
    const int bh  = bid % 64;
    const int qt  = (NQT - 1) - bid / 64;
    const int b   = bh / NKV;
    const int hk  = bh % NKV;
    const int g   = w >> 1;
    const int h   = hk * GQ + g;
    const int rh  = (w & 1) * 32;

    const long qtok0 = (long)b * SEQ + qt * QBLK;

    bf16x8 aq[2][4];
    #pragma unroll
    for (int f = 0; f < 2; ++f) {
        const float* qp = qg + (qtok0 + rh + f * 16 + l16) * QD + h * HDIM + l4 * 8;
        #pragma unroll
        for (int s = 0; s < 4; ++s) {
            float4 x = *(const float4*)(qp + s * 32);
            float4 y = *(const float4*)(qp + s * 32 + 4);
            bf16x8 t;
            t[0] = (bf16_t)x.x; t[1] = (bf16_t)x.y; t[2] = (bf16_t)x.z; t[3] = (bf16_t)x.w;
            t[4] = (bf16_t)y.x; t[5] = (bf16_t)y.y; t[6] = (bf16_t)y.z; t[7] = (bf16_t)y.w;
            aq[f][s] = t;
        }
    }

    f32x4 accO[2][8];
    float mrun[2][4], lsum[2][4];
    #pragma unroll
    for (int f = 0; f < 2; ++f) {
        #pragma unroll
        for (int n = 0; n < 8; ++n) accO[f][n] = (f32x4){0.f, 0.f, 0.f, 0.f};
        #pragma unroll
        for (int j = 0; j < 4; ++j) { mrun[f][j] = -1e30f; lsum[f][j] = 0.f; }
    }

    const long ktok0 = (long)b * SEQ;
    const int nkt = qt + 1;

    for (int kt = 0; kt < nkt; ++kt) {
        __syncthreads();
        const float* kp = kg + (ktok0 + kt * KBLK) * KVD + hk * HDIM;
        const float* vp = vg + (ktok0 + kt * KBLK) * KVD + hk * HDIM;
        #pragma unroll
        for (int it = 0; it < 4; ++it) {
            int idx = it * 512 + tid;
            int row = idx >> 5;
            int c4  = (idx & 31) * 4;
            float4 kf = *(const float4*)(kp + (long)row * KVD + c4);
            bf16x4 k4;
            k4[0] = (bf16_t)kf.x; k4[1] = (bf16_t)kf.y; k4[2] = (bf16_t)kf.z; k4[3] = (bf16_t)kf.w;
            *(bf16x4*)(&Kl[row * KPAD + c4]) = k4;
            float4 vf = *(const float4*)(vp + (long)row * KVD + c4);
            const float* vfa = (const float*)&vf;
            #pragma unroll
            for (int m = 0; m < 4; ++m) {
                int d   = c4 + m;
                int blk = (row >> 3) ^ ((d >> 3) & 7);
                Vt[d * VPAD + blk * 8 + (row & 7)] = (bf16_t)vfa[m];
            }
        }
        __syncthreads();

        const bool diag = (kt == qt);
        bf16_t* pw = &Pl[w * 16 * PPAD];

        #pragma unroll
        for (int f = 0; f < 2; ++f) {
            f32x4 accS[4];
            #pragma unroll
            for (int n = 0; n < 4; ++n) {
                f32x4 acc = (f32x4){0.f, 0.f, 0.f, 0.f};
                #pragma unroll
                for (int s = 0; s < 4; ++s) {
                    bf16x8 bk = *(const bf16x8*)(&Kl[(n * 16 + l16) * KPAD + s * 32 + l4 * 8]);
                    acc = __builtin_amdgcn_mfma_f32_16x16x32_bf16(aq[f][s], bk, acc, 0, 0, 0);
                }
                accS[n] = acc;
            }

            const int qrow_loc = rh + f * 16 + l4 * 4;
            float pm[4];
            #pragma unroll
            for (int j = 0; j < 4; ++j) pm[j] = -1e30f;
            #pragma unroll
            for (int n = 0; n < 4; ++n) {
                #pragma unroll
                for (int j = 0; j < 4; ++j) {
                    float sv = accS[n][j] * ATT_SCALE;
                    if (diag && (n * 16 + l16 > qrow_loc + j)) sv = -1e30f;
                    accS[n][j] = sv;
                    pm[j] = fmaxf(pm[j], sv);
                }
            }
            #pragma unroll
            for (int j = 0; j < 4; ++j) {
                float m0 = pm[j];
                m0 = fmaxf(m0, __shfl_xor(m0, 1));
                m0 = fmaxf(m0, __shfl_xor(m0, 2));
                m0 = fmaxf(m0, __shfl_xor(m0, 4));
                m0 = fmaxf(m0, __shfl_xor(m0, 8));
                pm[j] = m0;
            }
            float al[4], rs[4];
            #pragma unroll
            for (int j = 0; j < 4; ++j) {
                float mnew = fmaxf(mrun[f][j], pm[j]);
                al[j] = __expf(mrun[f][j] - mnew);
                mrun[f][j] = mnew;
                rs[j] = 0.f;
            }
            #pragma unroll
            for (int n = 0; n < 4; ++n) {
                #pragma unroll
                for (int j = 0; j < 4; ++j) {
                    float p = __expf(accS[n][j] - mrun[f][j]);
                    accS[n][j] = p;
                    rs[j] += p;
                }
            }
            #pragma unroll
            for (int j = 0; j < 4; ++j) {
                float r = rs[j];
                r += __shfl_xor(r, 1);
                r += __shfl_xor(r, 2);
                r += __shfl_xor(r, 4);
                r += __shfl_xor(r, 8);
                lsum[f][j] = lsum[f][j] * al[j] + r;
            }
            #pragma unroll
            for (int n = 0; n < 8; ++n) {
                #pragma unroll
                for (int j = 0; j < 4; ++j) accO[f][n][j] *= al[j];
            }
            #pragma unroll
            for (int n = 0; n < 4; ++n) {
                #pragma unroll
                for (int j = 0; j < 4; ++j)
                    pw[(l4 * 4 + j) * PPAD + n * 16 + l16] = (bf16_t)accS[n][j];
            }
            asm volatile("s_waitcnt lgkmcnt(0)" ::: "memory");
            __builtin_amdgcn_sched_barrier(0);
            #pragma unroll
            for (int ks = 0; ks < 2; ++ks) {
                bf16x8 ap = *(const bf16x8*)(&pw[l16 * PPAD + ks * 32 + l4 * 8]);
                #pragma unroll
                for (int n = 0; n < 8; ++n) {
                    int d   = n * 16 + l16;
                    int blk = (ks * 4 + l4) ^ ((d >> 3) & 7);
                    bf16x8 bv = *(const bf16x8*)(&Vt[d * VPAD + blk * 8]);
                    accO[f][n] = __builtin_amdgcn_mfma_f32_16x16x32_bf16(ap, bv, accO[f][n], 0, 0, 0);
                }
            }
        }
    }

    #pragma unroll
    for (int f = 0; f < 2; ++f) {
        #pragma unroll
        for (int j = 0; j < 4; ++j) {
            float inv = 1.f / lsum[f][j];
            float* op = og + (qtok0 + rh + f * 16 + l4 * 4 + j) * QD + h * HDIM;
            #pragma unroll
            for (int n = 0; n < 8; ++n)
                op[n * 16 + l16] = accO[f][n][j] * inv;
        }
    }
}

extern "C" void kernel_launch(void* const* d_in, const int* in_sizes, int n_in,
                              void* d_out, int out_size, void* d_ws, size_t ws_size,
                              hipStream_t stream) {
    const float* q = (const float*)d_in[0];
    const float* k = (const float*)d_in[1];
    const float* v = (const float*)d_in[2];
    float* o = (float*)d_out;

    const size_t kws_elems = (size_t)TOTAL * KVD;            // 8,388,608
    const size_t vws_elems = (size_t)BATCH * NKV * HDIM * SEQ;
    const size_t need = (kws_elems + vws_elems) * sizeof(bf16_t);  // 33.5 MB

    if (ws_size >= need) {
        bf16_t* kws  = (bf16_t*)d_ws;
        bf16_t* vtws = kws + kws_elems;
        attn_prepass_kernel<<<1536, 256, 0, stream>>>(k, v, kws, vtws);
        attn_fwd_v15<<<1024, 512, 0, stream>>>(q, kws, vtws, o);
    } else {
        attn_fwd_v1<<<NQT * BATCH * NKV, 512, 0, stream>>>(q, k, v, o);
    }
}

// Round 17
// 139.892 us; speedup vs baseline: 1.2473x; 1.0051x over previous
//
#include <hip/hip_runtime.h>
#include <hip/hip_bf16.h>
#include <stdint.h>

typedef __bf16 bf16_t;
typedef __attribute__((ext_vector_type(8))) __bf16 bf16x8;
typedef __attribute__((ext_vector_type(4))) __bf16 bf16x4;
typedef __attribute__((ext_vector_type(4))) float f32x4;

#define NHEADS 32
#define HDIM 128
#define NKV 8
#define GQ 4
#define BATCH 8
#define SEQ 1024
#define TOTAL (BATCH * SEQ)
#define QD (NHEADS * HDIM)   // 4096
#define KVD (NKV * HDIM)     // 1024
#define ATT_SCALE 0.08838834764831845f
#define QSCL (0.08838834764831845f * 1.4426950408889634f)

#define QBLK 64
#define KBLK 64
#define NQT (SEQ / QBLK)     // 16

#if __has_builtin(__builtin_amdgcn_exp2f)
#define EXP2F __builtin_amdgcn_exp2f   // raw v_exp_f32; args bounded ~|30|
#else
#define EXP2F exp2f
#endif

__device__ __forceinline__ void gload16(const bf16_t* g, bf16_t* l) {
    __builtin_amdgcn_global_load_lds(
        (const __attribute__((address_space(1))) void*)g,
        (__attribute__((address_space(3))) void*)l,
        16, 0, 0);
}

// proven in m214v22 / v8: pack two f32 -> u32 of 2 bf16 (lo = src0, hi = src1)
__device__ __forceinline__ uint32_t cvt_pk_bf16(float lo, float hi) {
    uint32_t r;
    asm("v_cvt_pk_bf16_f32 %0, %1, %2" : "=v"(r) : "v"(lo), "v"(hi));
    return r;
}

// ===========================================================================
// Pre-pass: K fp32 -> bf16 (same layout); V fp32 -> bf16 TRANSPOSED with
// k-column PERMUTATION within each 64-token block:
//   k = (k5 k4 k3 k2 k1 k0) -> pos = k5<<5 | k3<<4 | k2<<3 | k4<<2 | k1 k0
// Makes the PV B-fragment (chunk ks*4+l4) match the k's a lane holds
// in-register after the swapped QK^T -> P->A pack is fully in-lane.
// ===========================================================================
__global__ __launch_bounds__(256)
void attn_prepass_kernel(const float* __restrict__ kg, const float* __restrict__ vg,
                         bf16_t* __restrict__ kws, bf16_t* __restrict__ vtws)
{
    const int bid = blockIdx.x;
    const int tid = threadIdx.x;
    if (bid < 512) {
        __shared__ bf16_t Lt[128 * 130];
        const int b  = bid >> 6;
        const int hk = (bid >> 3) & 7;
        const int tt = bid & 7;
        const float* vp = vg + ((long)(b * SEQ + tt * 128)) * KVD + hk * HDIM;
        #pragma unroll
        for (int it = 0; it < 16; ++it) {
            int idx = it * 256 + tid;
            int t  = idx >> 5;
            int c4 = (idx & 31) * 4;
            float4 f = *(const float4*)(vp + (long)t * KVD + c4);
            Lt[(c4 + 0) * 130 + t] = (bf16_t)f.x;
            Lt[(c4 + 1) * 130 + t] = (bf16_t)f.y;
            Lt[(c4 + 2) * 130 + t] = (bf16_t)f.z;
            Lt[(c4 + 3) * 130 + t] = (bf16_t)f.w;
        }
        __syncthreads();
        bf16_t* op = vtws + ((long)((b * NKV + hk) * HDIM)) * SEQ + tt * 128;
        #pragma unroll
        for (int jt = 0; jt < 8; ++jt) {
            int jdx = jt * 256 + tid;
            int d  = jdx >> 4;          // 0..127
            int c8 = (jdx & 15) * 8;    // 0..120 (8-aligned)
            const bf16_t* lp = &Lt[d * 130 + c8];
            uint32_t u0 = *(const uint32_t*)(lp + 0);
            uint32_t u1 = *(const uint32_t*)(lp + 2);
            uint32_t u2 = *(const uint32_t*)(lp + 4);
            uint32_t u3 = *(const uint32_t*)(lp + 6);
            // chunk base kl0 (bits k5,k4,k3) -> pos base p0 = k5<<5|k3<<4|k4<<2
            int kl0 = c8 & 63;
            int p0  = (kl0 & 32) | ((kl0 & 8) << 1) | ((kl0 & 16) >> 2);
            bf16_t* dst = op + (long)d * SEQ + (c8 & ~63);
            uint2 lo; lo.x = u0; lo.y = u1;     // k2=0: j=0..3
            uint2 hi; hi.x = u2; hi.y = u3;     // k2=1: j=0..3
            *(uint2*)(dst + p0)     = lo;
            *(uint2*)(dst + p0 + 8) = hi;
        }
    } else {
        const long total4 = (long)TOTAL * KVD / 4;
        const float4* k4 = (const float4*)kg;
        for (long i = (long)(bid - 512) * 256 + tid; i < total4; i += 1024L * 256) {
            float4 f = k4[i];
            bf16x4 o4;
            o4[0] = (bf16_t)f.x; o4[1] = (bf16_t)f.y;
            o4[2] = (bf16_t)f.z; o4[3] = (bf16_t)f.w;
            *(bf16x4*)(kws + i * 4) = o4;
        }
    }
}

// ===========================================================================
// Main attention kernel (v16 = v15 + diagonal-tile PV skip).
//   v15 structure: swapped QK^T in-reg softmax, in-lane P->A pack via V
//   k-perm, 2-deep gload_lds staging, issue-1-ahead single barrier, XOR
//   swizzle, balanced pairing, XCD-aware bid decode, 2 blocks/CU, fused QK
//   chains under one setprio region, raw v_exp.
//   NEW: on the diagonal tile, waves fs<=1 have pa[1] == 0 (kb 2,3 fully
//   masked) -> their 8 ks=1 PV MFMAs + 8 LDS reads are zero-work; skip with
//   one uniform branch. (Bank-conflict audit r16: QK/PV/staging patterns are
//   all at the wave64-b128 minimum; the 8.5e6 counter is intrinsic.)
// ===========================================================================
__global__ __launch_bounds__(512, 4)
void attn_fwd_v16(const float* __restrict__ qg, const bf16_t* __restrict__ kws,
                  const bf16_t* __restrict__ vtws, float* __restrict__ og)
{
    __shared__ __align__(16) bf16_t Kl[2][KBLK * HDIM];   // 2 x 16KB, [64][128]
    __shared__ __align__(16) bf16_t Vl[2][HDIM * KBLK];   // 2 x 16KB, [128][64]

    const int tid  = threadIdx.x;
    const int w    = tid >> 6;    // 0..7
    const int lane = tid & 63;
    const int l16  = lane & 15;
    const int l4   = lane >> 4;   // 0..3

    // XCD-aware decode: hk in the low 3 bits (HW maps bid%8 -> XCD).
    const int bid = blockIdx.x;        // 0..1023
    const int hk  = bid & 7;
    const int m   = bid >> 3;          // 0..127
    const int hp  = m & 1;             // head-pair within kv group
    const int b   = (m >> 1) & 7;
    const int pi  = m >> 4;            // 0..7
    const int g2  = w >> 2;            // head within pair
    const int fs  = w & 3;             // 16-row slot in 64-row q-tile
    const int h   = hk * GQ + hp * 2 + g2;

    const bf16_t* kbase = kws + (long)(b * SEQ) * KVD + hk * HDIM;
    const bf16_t* vbase = vtws + (long)((b * NKV + hk) * HDIM) * SEQ;
    const int kc0 = w * 2;

    // ---- tile-invariant per-lane staging offsets ----
    long koff[2], voff[2];
    int ldst[2];
    #pragma unroll
    for (int i = 0; i < 2; ++i) {
        int c = kc0 + i;
        int r = c * 4 + (lane >> 4);
        koff[i] = (long)r * KVD + (((lane & 15) ^ (r & 7)) * 8);
        int d = c * 8 + (lane >> 3);
        voff[i] = (long)d * SEQ + (((lane & 7) ^ (d & 7)) * 8);
        ldst[i] = c * 512;
    }
    const long KT_STRIDE = (long)KBLK * KVD;   // 65536 elems

    for (int ph = 0; ph < 2; ++ph) {
        const int qt = ph ? pi : (NQT - 1 - pi);   // heavy q-tile first
        const long qtok0 = (long)b * SEQ + qt * QBLK;

        // ---- Q fragments (B-op): col = l16 (q-row), k-slots d = s*32+l4*8+e ----
        bf16x8 aq[4];
        {
            const float* qp = qg + (qtok0 + fs * 16 + l16) * QD + h * HDIM + l4 * 8;
            #pragma unroll
            for (int s = 0; s < 4; ++s) {
                float4 x = *(const float4*)(qp + s * 32);
                float4 y = *(const float4*)(qp + s * 32 + 4);
                bf16x8 t;
                t[0] = (bf16_t)(x.x * QSCL); t[1] = (bf16_t)(x.y * QSCL);
                t[2] = (bf16_t)(x.z * QSCL); t[3] = (bf16_t)(x.w * QSCL);
                t[4] = (bf16_t)(y.x * QSCL); t[5] = (bf16_t)(y.y * QSCL);
                t[6] = (bf16_t)(y.z * QSCL); t[7] = (bf16_t)(y.w * QSCL);
                aq[s] = t;
            }
        }
        __builtin_amdgcn_sched_barrier(0);
        __syncthreads();   // phase boundary: prev phase's LDS reads done

        f32x4 accO[8];
        #pragma unroll
        for (int n = 0; n < 8; ++n) accO[n] = (f32x4){0.f, 0.f, 0.f, 0.f};
        float rsum[4] = {0.f, 0.f, 0.f, 0.f};

        const bf16_t* kn = kbase;
        const bf16_t* vn = vbase;
        auto issue_tile = [&](int buf) {
            gload16(kn + koff[0], &Kl[buf][ldst[0]]);
            gload16(kn + koff[1], &Kl[buf][ldst[1]]);
            gload16(vn + voff[0], &Vl[buf][ldst[0]]);
            gload16(vn + voff[1], &Vl[buf][ldst[1]]);
            kn += KT_STRIDE;
            vn += KBLK;
        };

        const int nkt = qt + 1;
        issue_tile(0);

        for (int kt = 0; kt < nkt; ++kt) {
            const bf16_t* Kc = &Kl[kt & 1][0];
            const bf16_t* Vc = &Vl[kt & 1][0];
            // own loads for tile kt are the only outstanding ones here
            asm volatile("s_waitcnt vmcnt(0)" ::: "memory");
            __builtin_amdgcn_s_barrier();
            if (kt + 1 < nkt) issue_tile((kt + 1) & 1);
            __builtin_amdgcn_sched_barrier(0);

            const bool diag = (kt == qt);

            // ---- QK: 4 INDEPENDENT MFMA chains, one setprio region ----
            f32x4 t[4];
            __builtin_amdgcn_s_setprio(1);
            #pragma unroll
            for (int kb = 0; kb < 4; ++kb) {
                if (!(diag && (kb > fs))) {
                    f32x4 acc = (f32x4){0.f, 0.f, 0.f, 0.f};
                    #pragma unroll
                    for (int s = 0; s < 4; ++s) {
                        int elem = (s * 32 + l4 * 8) ^ ((l16 & 7) << 3);
                        bf16x8 bk = *(const bf16x8*)(Kc + (kb * 16 + l16) * 128 + elem);
                        acc = __builtin_amdgcn_mfma_f32_16x16x32_bf16(bk, aq[s], acc, 0, 0, 0);
                    }
                    t[kb] = acc;
                }
            }
            __builtin_amdgcn_s_setprio(0);

            // ---- softmax + pack as a second pass over t[4] ----
            uint32_t u[4][2];
            #pragma unroll
            for (int kb = 0; kb < 4; ++kb) { u[kb][0] = 0; u[kb][1] = 0; }
            #pragma unroll
            for (int kb = 0; kb < 4; ++kb) {
                if (!(diag && (kb > fs))) {
                    const bool needmask = diag && (kb == fs);
                    #pragma unroll
                    for (int j = 0; j < 4; ++j) {
                        float p = EXP2F(t[kb][j]);
                        if (needmask && (kb * 16 + l4 * 4 + j > fs * 16 + l16)) p = 0.f;
                        t[kb][j] = p;
                        rsum[j] += p;   // 4 independent chains
                    }
                    u[kb][0] = cvt_pk_bf16(t[kb][0], t[kb][1]);
                    u[kb][1] = cvt_pk_bf16(t[kb][2], t[kb][3]);
                }
            }

            // ---- P -> PV A-frags: IN-LANE (V k-perm makes B match) ----
            bf16x8 pa[2];
            #pragma unroll
            for (int ks = 0; ks < 2; ++ks) {
                union { uint32_t uu[4]; bf16x8 v; } pk;
                pk.uu[0] = u[ks * 2][0];
                pk.uu[1] = u[ks * 2][1];
                pk.uu[2] = u[ks * 2 + 1][0];
                pk.uu[3] = u[ks * 2 + 1][1];
                pa[ks] = pk.v;
            }

            // ---- O += P V ; on diag tiles, waves fs<=1 have pa[1]==0 ----
            const bool doks1 = !(diag && (fs <= 1));
            __builtin_amdgcn_s_setprio(1);
            #pragma unroll
            for (int n = 0; n < 8; ++n) {
                int elem = (l4 * 8) ^ ((l16 & 7) << 3);
                bf16x8 bv = *(const bf16x8*)(Vc + (n * 16 + l16) * 64 + elem);
                accO[n] = __builtin_amdgcn_mfma_f32_16x16x32_bf16(pa[0], bv, accO[n], 0, 0, 0);
            }
            if (doks1) {
                #pragma unroll
                for (int n = 0; n < 8; ++n) {
                    int elem = (32 + l4 * 8) ^ ((l16 & 7) << 3);
                    bf16x8 bv = *(const bf16x8*)(Vc + (n * 16 + l16) * 64 + elem);
                    accO[n] = __builtin_amdgcn_mfma_f32_16x16x32_bf16(pa[1], bv, accO[n], 0, 0, 0);
                }
            }
            __builtin_amdgcn_s_setprio(0);
            // no end-of-tile barrier (issue-1-ahead scheme)
        }

        // ---- epilogue: combine partials, reduce over l4 group, store ----
        float rs = (rsum[0] + rsum[1]) + (rsum[2] + rsum[3]);
        rs += __shfl_xor(rs, 16);
        rs += __shfl_xor(rs, 32);
        float inv = 1.f / rs;   // valid for q-row = l16 on every lane
        #pragma unroll
        for (int j = 0; j < 4; ++j) {
            const int qr = l4 * 4 + j;
            float invr = __shfl(inv, qr);   // lane qr holds q-row qr's inv
            float* op = og + (qtok0 + fs * 16 + qr) * QD + h * HDIM + l16;
            #pragma unroll
            for (int n = 0; n < 8; ++n)
                op[n * 16] = accO[n][j] * invr;
        }
    }
}

// ===========================================================================
// Fallback (round-1 kernel) if ws is too small for the bf16 pre-pass.
// ===========================================================================
#define KPAD 136
#define VPAD 72
#define PPAD 72
__global__ __launch_bounds__(512, 2)
void attn_fwd_v1(const float* __restrict__ qg, const float* __restrict__ kg,
                 const float* __restrict__ vg, float* __restrict__ og)
{
    __shared__ bf16_t Kl[KBLK * KPAD];
    __shared__ bf16_t Vt[HDIM * VPAD];
    __shared__ bf16_t Pl[8 * 16 * PPAD];

    const int tid  = threadIdx.x;
    const int w    = tid >> 6;
    const int lane = tid & 63;
    const int l4   = lane >> 4;
    const int l16  = lane & 15;

    const int bid = blockIdx.x;
    const int bh  = bid % 64;
    const int qt  = (NQT - 1) - bid / 64;
    const int b   = bh / NKV;
    const int hk  = bh % NKV;
    const int g   = w >> 1;
    const int h   = hk * GQ + g;
    const int rh  = (w & 1) * 32;

    const long qtok0 = (long)b * SEQ + qt * QBLK;

    bf16x8 aq[2][4];
    #pragma unroll
    for (int f = 0; f < 2; ++f) {
        const float* qp = qg + (qtok0 + rh + f * 16 + l16) * QD + h * HDIM + l4 * 8;
        #pragma unroll
        for (int s = 0; s < 4; ++s) {
            float4 x = *(const float4*)(qp + s * 32);
            float4 y = *(const float4*)(qp + s * 32 + 4);
            bf16x8 t;
            t[0] = (bf16_t)x.x; t[1] = (bf16_t)x.y; t[2] = (bf16_t)x.z; t[3] = (bf16_t)x.w;
            t[4] = (bf16_t)y.x; t[5] = (bf16_t)y.y; t[6] = (bf16_t)y.z; t[7] = (bf16_t)y.w;
            aq[f][s] = t;
        }
    }

    f32x4 accO[2][8];
    float mrun[2][4], lsum[2][4];
    #pragma unroll
    for (int f = 0; f < 2; ++f) {
        #pragma unroll
        for (int n = 0; n < 8; ++n) accO[f][n] = (f32x4){0.f, 0.f, 0.f, 0.f};
        #pragma unroll
        for (int j = 0; j < 4; ++j) { mrun[f][j] = -1e30f; lsum[f][j] = 0.f; }
    }

    const long ktok0 = (long)b * SEQ;
    const int nkt = qt + 1;

    for (int kt = 0; kt < nkt; ++kt) {
        __syncthreads();
        const float* kp = kg + (ktok0 + kt * KBLK) * KVD + hk * HDIM;
        const float* vp = vg + (ktok0 + kt * KBLK) * KVD + hk * HDIM;
        #pragma unroll
        for (int it = 0; it < 4; ++it) {
            int idx = it * 512 + tid;
            int row = idx >> 5;
            int c4  = (idx & 31) * 4;
            float4 kf = *(const float4*)(kp + (long)row * KVD + c4);
            bf16x4 k4;
            k4[0] = (bf16_t)kf.x; k4[1] = (bf16_t)kf.y; k4[2] = (bf16_t)kf.z; k4[3] = (bf16_t)kf.w;
            *(bf16x4*)(&Kl[row * KPAD + c4]) = k4;
            float4 vf = *(const float4*)(vp + (long)row * KVD + c4);
            const float* vfa = (const float*)&vf;
            #pragma unroll
            for (int m = 0; m < 4; ++m) {
                int d   = c4 + m;
                int blk = (row >> 3) ^ ((d >> 3) & 7);
                Vt[d * VPAD + blk * 8 + (row & 7)] = (bf16_t)vfa[m];
            }
        }
        __syncthreads();

        const bool diag = (kt == qt);
        bf16_t* pw = &Pl[w * 16 * PPAD];

        #pragma unroll
        for (int f = 0; f < 2; ++f) {
            f32x4 accS[4];
            #pragma unroll
            for (int n = 0; n < 4; ++n) {
                f32x4 acc = (f32x4){0.f, 0.f, 0.f, 0.f};
                #pragma unroll
                for (int s = 0; s < 4; ++s) {
                    bf16x8 bk = *(const bf16x8*)(&Kl[(n * 16 + l16) * KPAD + s * 32 + l4 * 8]);
                    acc = __builtin_amdgcn_mfma_f32_16x16x32_bf16(aq[f][s], bk, acc, 0, 0, 0);
                }
                accS[n] = acc;
            }

            const int qrow_loc = rh + f * 16 + l4 * 4;
            float pm[4];
            #pragma unroll
            for (int j = 0; j < 4; ++j) pm[j] = -1e30f;
            #pragma unroll
            for (int n = 0; n < 4; ++n) {
                #pragma unroll
                for (int j = 0; j < 4; ++j) {
                    float sv = accS[n][j] * ATT_SCALE;
                    if (diag && (n * 16 + l16 > qrow_loc + j)) sv = -1e30f;
                    accS[n][j] = sv;
                    pm[j] = fmaxf(pm[j], sv);
                }
            }
            #pragma unroll
            for (int j = 0; j < 4; ++j) {
                float m0 = pm[j];
                m0 = fmaxf(m0, __shfl_xor(m0, 1));
                m0 = fmaxf(m0, __shfl_xor(m0, 2));
                m0 = fmaxf(m0, __shfl_xor(m0, 4));
                m0 = fmaxf(m0, __shfl_xor(m0, 8));
                pm[j] = m0;
            }
            float al[4], rs[4];
            #pragma unroll
            for (int j = 0; j < 4; ++j) {
                float mnew = fmaxf(mrun[f][j], pm[j]);
                al[j] = __expf(mrun[f][j] - mnew);
                mrun[f][j] = mnew;
                rs[j] = 0.f;
            }
            #pragma unroll
            for (int n = 0; n < 4; ++n) {
                #pragma unroll
                for (int j = 0; j < 4; ++j) {
                    float p = __expf(accS[n][j] - mrun[f][j]);
                    accS[n][j] = p;
                    rs[j] += p;
                }
            }
            #pragma unroll
            for (int j = 0; j < 4; ++j) {
                float r = rs[j];
                r += __shfl_xor(r, 1);
                r += __shfl_xor(r, 2);
                r += __shfl_xor(r, 4);
                r += __shfl_xor(r, 8);
                lsum[f][j] = lsum[f][j] * al[j] + r;
            }
            #pragma unroll
            for (int n = 0; n < 8; ++n) {
                #pragma unroll
                for (int j = 0; j < 4; ++j) accO[f][n][j] *= al[j];
            }
            #pragma unroll
            for (int n = 0; n < 4; ++n) {
                #pragma unroll
                for (int j = 0; j < 4; ++j)
                    pw[(l4 * 4 + j) * PPAD + n * 16 + l16] = (bf16_t)accS[n][j];
            }
            asm volatile("s_waitcnt lgkmcnt(0)" ::: "memory");
            __builtin_amdgcn_sched_barrier(0);
            #pragma unroll
            for (int ks = 0; ks < 2; ++ks) {
                bf16x8 ap = *(const bf16x8*)(&pw[l16 * PPAD + ks * 32 + l4 * 8]);
                #pragma unroll
                for (int n = 0; n < 8; ++n) {
                    int d   = n * 16 + l16;
                    int blk = (ks * 4 + l4) ^ ((d >> 3) & 7);
                    bf16x8 bv = *(const bf16x8*)(&Vt[d * VPAD + blk * 8]);
                    accO[f][n] = __builtin_amdgcn_mfma_f32_16x16x32_bf16(ap, bv, accO[f][n], 0, 0, 0);
                }
            }
        }
    }

    #pragma unroll
    for (int f = 0; f < 2; ++f) {
        #pragma unroll
        for (int j = 0; j < 4; ++j) {
            float inv = 1.f / lsum[f][j];
            float* op = og + (qtok0 + rh + f * 16 + l4 * 4 + j) * QD + h * HDIM;
            #pragma unroll
            for (int n = 0; n < 8; ++n)
                op[n * 16 + l16] = accO[f][n][j] * inv;
        }
    }
}

extern "C" void kernel_launch(void* const* d_in, const int* in_sizes, int n_in,
                              void* d_out, int out_size, void* d_ws, size_t ws_size,
                              hipStream_t stream) {
    const float* q = (const float*)d_in[0];
    const float* k = (const float*)d_in[1];
    const float* v = (const float*)d_in[2];
    float* o = (float*)d_out;

    const size_t kws_elems = (size_t)TOTAL * KVD;            // 8,388,608
    const size_t vws_elems = (size_t)BATCH * NKV * HDIM * SEQ;
    const size_t need = (kws_elems + vws_elems) * sizeof(bf16_t);  // 33.5 MB

    if (ws_size >= need) {
        bf16_t* kws  = (bf16_t*)d_ws;
        bf16_t* vtws = kws + kws_elems;
        attn_prepass_kernel<<<1536, 256, 0, stream>>>(k, v, kws, vtws);
        attn_fwd_v16<<<1024, 512, 0, stream>>>(q, kws, vtws, o);
    } else {
        attn_fwd_v1<<<NQT * BATCH * NKV, 512, 0, stream>>>(q, k, v, o);
    }
}